// Round 4
// baseline (479.683 us; speedup 1.0000x reference)
//
#include <hip/hip_runtime.h>
#include <math.h>

// Heatmap peak detection: 3x3 max-pool (stride 1, -inf pad) identity mask,
// gated by sigmoid(x) > 0.05. Input [16,17,512,512] f32 = 272 planes 512x512.
//
// Register-rolling 3-row window, no LDS, no barriers. Each wave streams a
// 256-float-wide chunk over a 64-row strip; horizontal halo via shfl from
// neighbor lanes (they already hold the adjacent float4), plus one predicated
// scalar load on the wave-edge lane for the cross-chunk column.
#define HM_W 512
#define HM_H 512
#define STRIP 64            // rows per wave; vertical halo amp = 66/64 = 1.031x
#define SIG_THRESH 0.05f

__global__ __launch_bounds__(256) void heatmap_peak_kernel(
    const float* __restrict__ in, float* __restrict__ out) {
    const int lane  = threadIdx.x;                 // 0..63 (one wave per ty)
    const int chunk = blockIdx.x;                  // 0..1: which 256-float half-row
    const int x0    = chunk * 256 + lane * 4;      // this lane's float4 column
    const int ys    = blockIdx.y * (4 * STRIP) + threadIdx.y * STRIP;
    const long long base = (long long)blockIdx.z * (long long)(HM_H * HM_W);
    const float* plane = in + base;

    const bool lane0  = (lane == 0);
    const bool lane63 = (lane == 63);
    const bool need_l = lane0  && (x0 > 0);        // cross-chunk left scalar
    const bool need_r = lane63 && (x0 + 4 < HM_W); // cross-chunk right scalar

    // Load row y: float4 + resolved left/right halo scalars for this lane.
    // (y-condition is wave-uniform, so the shfls inside are safe.)
    auto load_row = [&](int y, float4& v, float& l, float& r) {
        if (y >= 0 && y < HM_H) {
            const float* rp = plane + (long long)y * HM_W;
            v = *(const float4*)(rp + x0);
            const float le = need_l ? rp[x0 - 1] : -INFINITY;
            const float re = need_r ? rp[x0 + 4] : -INFINITY;
            l = __shfl_up(v.w, 1);
            if (lane0) l = le;
            r = __shfl_down(v.x, 1);
            if (lane63) r = re;
        } else {
            v = make_float4(-INFINITY, -INFINITY, -INFINITY, -INFINITY);
            l = -INFINITY;
            r = -INFINITY;
        }
    };

    // Rolling window: a = row y-1, b = row y (center), c = row y+1.
    float4 a, b;
    float la, lb, ra, rb;
    load_row(ys - 1, a, la, ra);
    load_row(ys,     b, lb, rb);

    #pragma unroll 4
    for (int k = 0; k < STRIP; ++k) {
        const int y = ys + k;
        float4 c;
        float lc, rc;
        load_row(y + 1, c, lc, rc);

        // vertical max over the 3 window rows
        float4 vm;
        vm.x = fmaxf(fmaxf(a.x, b.x), c.x);
        vm.y = fmaxf(fmaxf(a.y, b.y), c.y);
        vm.z = fmaxf(fmaxf(a.z, b.z), c.z);
        vm.w = fmaxf(fmaxf(a.w, b.w), c.w);
        const float lm = fmaxf(fmaxf(la, lb), lc);
        const float rm = fmaxf(fmaxf(ra, rb), rc);

        // horizontal max over 3 columns
        float4 hm;
        hm.x = fmaxf(lm,   fmaxf(vm.x, vm.y));
        hm.y = fmaxf(vm.x, fmaxf(vm.y, vm.z));
        hm.z = fmaxf(vm.y, fmaxf(vm.z, vm.w));
        hm.w = fmaxf(vm.z, fmaxf(vm.w, rm));

        // peak mask + sigmoid score (center row = b)
        float4 o;
        {
            const float sc = 1.0f / (1.0f + __expf(-b.x));
            o.x = (hm.x == b.x && sc > SIG_THRESH) ? sc : 0.0f;
        }
        {
            const float sc = 1.0f / (1.0f + __expf(-b.y));
            o.y = (hm.y == b.y && sc > SIG_THRESH) ? sc : 0.0f;
        }
        {
            const float sc = 1.0f / (1.0f + __expf(-b.z));
            o.z = (hm.z == b.z && sc > SIG_THRESH) ? sc : 0.0f;
        }
        {
            const float sc = 1.0f / (1.0f + __expf(-b.w));
            o.w = (hm.w == b.w && sc > SIG_THRESH) ? sc : 0.0f;
        }

        *(float4*)(out + base + (long long)y * HM_W + x0) = o;

        // roll the window down one row
        a = b; b = c;
        la = lb; lb = lc;
        ra = rb; rb = rc;
    }
}

extern "C" void kernel_launch(void* const* d_in, const int* in_sizes, int n_in,
                              void* d_out, int out_size, void* d_ws, size_t ws_size,
                              hipStream_t stream) {
    const float* heatmaps = (const float*)d_in[0];
    float* out = (float*)d_out;

    const int planes = in_sizes[0] / (HM_H * HM_W);  // B*num_kps = 272

    dim3 block(64, 4, 1);                    // 4 waves: 4 vertical strips of a chunk
    dim3 grid(2, HM_H / (4 * STRIP), planes);  // 2 x 2 x 272 = 1088 blocks
    heatmap_peak_kernel<<<grid, block, 0, stream>>>(heatmaps, out);
}

// Round 5
// 460.631 us; speedup vs baseline: 1.0414x; 1.0414x over previous
//
#include <hip/hip_runtime.h>
#include <math.h>

// Heatmap peak detection: 3x3 max-pool (stride 1, -inf pad) identity mask,
// gated by sigmoid(x) > 0.05. Input [16,17,512,512] f32 = 272 planes 512x512.
//
// R1 structure (bulk LDS staging + plain stores — measured best) with
// TILE_ROWS=16 (halo amp 18/16 = 1.125x vs R1's 6/4 = 1.5x).
#define HM_W 512
#define HM_H 512
#define TILE_ROWS 16
#define HALO_ROWS (TILE_ROWS + 2)
#define LDS_STRIDE 516               // 512 + 4 floats pad (16B-aligned stride)
#define SIG_THRESH 0.05f

__global__ __launch_bounds__(512) void heatmap_peak_kernel(
    const float* __restrict__ in, float* __restrict__ out) {
    // 18 rows x 516 cols = 37.2 KB LDS -> 4 blocks/CU (32 waves, full occupancy).
    __shared__ float s[HALO_ROWS][LDS_STRIDE];

    const int tx = threadIdx.x;             // 0..127  (float4 column)
    const int ty = threadIdx.y;             // 0..3
    const int t  = ty * 128 + tx;           // flat 0..511
    const int y0 = blockIdx.y * TILE_ROWS;  // first output row of tile
    const long long base = (long long)blockIdx.z * (long long)(HM_H * HM_W);

    // ---- Stage 18 rows: 2304 float4 loads over 512 threads (4.5 rounds) ----
    for (int i = t; i < HALO_ROWS * 128; i += 512) {
        const int r  = i >> 7;        // LDS row 0..17
        const int c  = i & 127;       // vec4 col
        const int gy = y0 - 1 + r;    // global row (halo: y0-1 .. y0+16)
        float4 v;
        if (gy >= 0 && gy < HM_H) {
            v = ((const float4*)(in + base + (long long)gy * HM_W))[c];
        } else {
            v = make_float4(-INFINITY, -INFINITY, -INFINITY, -INFINITY);
        }
        *(float4*)&s[r][c * 4] = v;
    }
    __syncthreads();

    const int x0   = tx * 4;
    const int row0 = ty * 4;   // this thread covers output rows row0..row0+3 (LDS-relative)
    const bool has_l = (x0 != 0);
    const bool has_r = (x0 + 4 < HM_W);

    // Rolling 3-row window: a = top, b = center, c4 = bottom.
    float4 a = *(const float4*)&s[row0][x0];
    float4 b = *(const float4*)&s[row0 + 1][x0];
    float la = has_l ? s[row0][x0 - 1]     : -INFINITY;
    float lb = has_l ? s[row0 + 1][x0 - 1] : -INFINITY;
    float ra = has_r ? s[row0][x0 + 4]     : -INFINITY;
    float rb = has_r ? s[row0 + 1][x0 + 4] : -INFINITY;

    #pragma unroll
    for (int k = 0; k < 4; ++k) {
        const int rr = row0 + k;               // window top LDS row; center = rr+1
        const float4 c4 = *(const float4*)&s[rr + 2][x0];
        const float  lc = has_l ? s[rr + 2][x0 - 1] : -INFINITY;
        const float  rc = has_r ? s[rr + 2][x0 + 4] : -INFINITY;

        // vertical max over 3 rows
        float4 vm;
        vm.x = fmaxf(fmaxf(a.x, b.x), c4.x);
        vm.y = fmaxf(fmaxf(a.y, b.y), c4.y);
        vm.z = fmaxf(fmaxf(a.z, b.z), c4.z);
        vm.w = fmaxf(fmaxf(a.w, b.w), c4.w);
        const float lm = fmaxf(fmaxf(la, lb), lc);
        const float rm = fmaxf(fmaxf(ra, rb), rc);

        // horizontal max over 3 columns
        float4 hm;
        hm.x = fmaxf(lm,   fmaxf(vm.x, vm.y));
        hm.y = fmaxf(vm.x, fmaxf(vm.y, vm.z));
        hm.z = fmaxf(vm.y, fmaxf(vm.z, vm.w));
        hm.w = fmaxf(vm.z, fmaxf(vm.w, rm));

        // peak mask + sigmoid score (center row = b)
        float4 o;
        {
            const float sc = 1.0f / (1.0f + __expf(-b.x));
            o.x = (hm.x == b.x && sc > SIG_THRESH) ? sc : 0.0f;
        }
        {
            const float sc = 1.0f / (1.0f + __expf(-b.y));
            o.y = (hm.y == b.y && sc > SIG_THRESH) ? sc : 0.0f;
        }
        {
            const float sc = 1.0f / (1.0f + __expf(-b.z));
            o.z = (hm.z == b.z && sc > SIG_THRESH) ? sc : 0.0f;
        }
        {
            const float sc = 1.0f / (1.0f + __expf(-b.w));
            o.w = (hm.w == b.w && sc > SIG_THRESH) ? sc : 0.0f;
        }

        // plain streaming store (nt hint measured as a regression in R3)
        ((float4*)(out + base + (long long)(y0 + rr) * HM_W))[tx] = o;

        // roll the window down one row
        a = b; b = c4;
        la = lb; lb = lc;
        ra = rb; rb = rc;
    }
}

extern "C" void kernel_launch(void* const* d_in, const int* in_sizes, int n_in,
                              void* d_out, int out_size, void* d_ws, size_t ws_size,
                              hipStream_t stream) {
    const float* heatmaps = (const float*)d_in[0];
    float* out = (float*)d_out;

    const int planes = in_sizes[0] / (HM_H * HM_W);  // B*num_kps = 272

    dim3 block(128, 4, 1);
    dim3 grid(1, HM_H / TILE_ROWS, planes);   // 1 x 32 x 272 = 8704 blocks
    heatmap_peak_kernel<<<grid, block, 0, stream>>>(heatmaps, out);
}